// Round 4
// baseline (3911.234 us; speedup 1.0000x reference)
//
#include <hip/hip_runtime.h>

typedef __attribute__((ext_vector_type(4))) float f32x4;
typedef __attribute__((ext_vector_type(8))) short s16x8;

#define N_NODES 65536
#define GNPG 1024
#define FDIM 64
#define HDIM 128
#define KNN 16
#define CAND 18
#define NEDGE (N_NODES * KNN)

__device__ __forceinline__ unsigned short f2bf(float f) {
  union { float f; unsigned int u; } v; v.f = f;
  unsigned int r = v.u + 0x7FFFu + ((v.u >> 16) & 1u);
  return (unsigned short)(r >> 16);
}
__device__ __forceinline__ float bf2f(unsigned short u) {
  union { unsigned int u; float f; } v; v.u = ((unsigned int)u) << 16;
  return v.f;
}

// Build MFMA B-fragment-ordered hi/lo bf16 split of W2 (128x128).
__global__ void prep_weights_k(const float* __restrict__ W2,
                               unsigned short* __restrict__ w2h, unsigned short* __restrict__ w2l) {
  int tid = threadIdx.x;
  for (int idx = tid; idx < 8 * 4 * 64 * 8; idx += 256) {
    int j = idx & 7, l = (idx >> 3) & 63, ks = (idx >> 9) & 3, ct = idx >> 11;
    int k = 8 * (l >> 4) + j + 32 * ks, col = ct * 16 + (l & 15);
    float v = W2[k * 128 + col];
    unsigned short hi = f2bf(v);
    w2h[idx] = hi;
    w2l[idx] = f2bf(v - bf2f(hi));
  }
}

// sq in f64 (exact reference-side values) + f32 copy for the candidate pass.
__global__ void prep_sq_k(const float* __restrict__ x, float* __restrict__ sq,
                          double* __restrict__ sq64) {
  int n = blockIdx.x * 256 + threadIdx.x;
  const f32x4* xp = (const f32x4*)(x + (size_t)n * FDIM);
  double s0 = 0, s1 = 0, s2 = 0, s3 = 0;
#pragma unroll
  for (int f = 0; f < 16; ++f) {
    f32x4 a = xp[f];
    s0 = fma((double)a[0], (double)a[0], s0);
    s1 = fma((double)a[1], (double)a[1], s1);
    s2 = fma((double)a[2], (double)a[2], s2);
    s3 = fma((double)a[3], (double)a[3], s3);
  }
  double s = (s0 + s1) + (s2 + s3);
  sq64[n] = s;
  sq[n] = (float)s;
}

// Full-fp32 GEMM1: PQ[n][0:128] = x[n]@(W1_top - W1_bot); PQ[n][128:256] = x[n]@W1_bot + b1.
__global__ __launch_bounds__(256) void prep_pq_k(const float* __restrict__ x,
                                                 const float* __restrict__ W1,
                                                 const float* __restrict__ b1,
                                                 float* __restrict__ PQ) {
  __shared__ float WcL[64 * 256];   // 64KB
  __shared__ float xL[16 * 64];     // 4KB
  int tid = threadIdx.x;
  for (int i = tid; i < 64 * 256; i += 256) {
    int k = i >> 8, c = i & 255;
    WcL[i] = (c < 128) ? (W1[k * 128 + c] - W1[(k + 64) * 128 + c])
                       : W1[(k + 64) * 128 + (c - 128)];
  }
  int nbase = blockIdx.x * 16;
  for (int i = tid; i < 16 * 64; i += 256) xL[i] = x[(size_t)nbase * 64 + i];
  __syncthreads();
  int nl = tid >> 4, c0 = tid & 15;
  float acc[16];
#pragma unroll
  for (int j = 0; j < 16; ++j) acc[j] = 0.f;
  for (int k = 0; k < 64; ++k) {
    float xk = xL[nl * 64 + k];
    const float* wr = WcL + k * 256 + c0;
#pragma unroll
    for (int j = 0; j < 16; ++j) acc[j] = fmaf(xk, wr[16 * j], acc[j]);
  }
#pragma unroll
  for (int j = 0; j < 16; ++j) {
    int c = c0 + 16 * j;
    float b = (c >= 128) ? b1[c - 128] : 0.f;
    PQ[(size_t)(nbase + nl) * 256 + c] = acc[j] + b;
  }
}

// KNN: 4 threads per center (j interleaved mod 4). Stage 1: fp32 top-18 of own 256-subset
// (register insertion, fully unrolled). Stage 2: unrolled f64 rescore + partial selection
// sort (top-16 of 18, (d,idx) order) -> LDS -> 4-way merge by sub-0 thread.
__global__ __launch_bounds__(256, 3) void knn_k(const float* __restrict__ x, const float* __restrict__ sq,
                                                const double* __restrict__ sq64,
                                                int* __restrict__ nbr, int* __restrict__ counts) {
  __shared__ float sq_l[GNPG];
  __shared__ double md[4][64][17];
  __shared__ unsigned short mi[4][64][17];
  int tid = threadIdx.x;
  int c_local = tid >> 2, s = tid & 3;
  int n = blockIdx.x * 64 + c_local;
  int gbase = (n >> 10) << 10;
  int nl = n & (GNPG - 1);
  for (int i = tid; i < GNPG; i += 256) sq_l[i] = sq[gbase + i];
  __syncthreads();
  f32x4 xi[16];
  const f32x4* xp = (const f32x4*)(x + (size_t)n * FDIM);
#pragma unroll
  for (int f = 0; f < 16; ++f) xi[f] = xp[f];
  float sqi = sq_l[nl];
  float dl[CAND]; int il[CAND];
#pragma unroll
  for (int q = 0; q < CAND; ++q) { dl[q] = 3.0e38f; il[q] = 0; }
  for (int i = 0; i < GNPG / 4; ++i) {
    int jl = 4 * i + s;
    const f32x4* xj = (const f32x4*)(x + (size_t)(gbase + jl) * FDIM);
    float s0 = 0, s1 = 0, s2 = 0, s3 = 0;
#pragma unroll
    for (int f = 0; f < 16; ++f) {
      f32x4 a = xi[f], b = xj[f];
      s0 = fmaf(a[0], b[0], s0); s1 = fmaf(a[1], b[1], s1);
      s2 = fmaf(a[2], b[2], s2); s3 = fmaf(a[3], b[3], s3);
    }
    float dot = (s0 + s1) + (s2 + s3);
    float d = sqi + sq_l[jl] - 2.f * dot;
    if (jl != nl && d < dl[CAND - 1]) {
      dl[CAND - 1] = d; il[CAND - 1] = jl;
#pragma unroll
      for (int p = CAND - 1; p >= 1; --p) {
        float a0 = dl[p - 1], a1 = dl[p];
        int b0 = il[p - 1], b1v = il[p];
        bool c = a1 < a0;
        dl[p - 1] = c ? a1 : a0; dl[p] = c ? a0 : a1;
        il[p - 1] = c ? b1v : b0; il[p] = c ? b0 : b1v;
      }
    }
  }
  // Stage 2: exact f64 distances for the 18 candidates (fully unrolled -> registers).
  double d64[CAND];
  double sq64i = sq64[n];
#pragma unroll
  for (int q = 0; q < CAND; ++q) {
    int j = gbase + il[q];
    const f32x4* xj = (const f32x4*)(x + (size_t)j * FDIM);
    double t0 = 0, t1 = 0, t2 = 0, t3 = 0;
#pragma unroll
    for (int f = 0; f < 16; ++f) {
      f32x4 a = xi[f], b = xj[f];
      t0 = fma((double)a[0], (double)b[0], t0);
      t1 = fma((double)a[1], (double)b[1], t1);
      t2 = fma((double)a[2], (double)b[2], t2);
      t3 = fma((double)a[3], (double)b[3], t3);
    }
    d64[q] = sq64i + sq64[j] - 2.0 * ((t0 + t1) + (t2 + t3));
  }
  // Partial selection sort: first 16 positions by (d64, idx).
#pragma unroll
  for (int a = 0; a < 16; ++a)
#pragma unroll
    for (int b = a + 1; b < CAND; ++b) {
      bool sw = (d64[b] < d64[a]) || (d64[b] == d64[a] && il[b] < il[a]);
      double td = sw ? d64[b] : d64[a];
      double tu = sw ? d64[a] : d64[b];
      int ti = sw ? il[b] : il[a];
      int tv = sw ? il[a] : il[b];
      d64[a] = td; d64[b] = tu; il[a] = ti; il[b] = tv;
    }
#pragma unroll
  for (int q = 0; q < 16; ++q) {
    md[s][c_local][q] = d64[q];
    mi[s][c_local][q] = (unsigned short)il[q];
  }
  __syncthreads();
  if (s == 0) {
    int p0 = 0, p1 = 0, p2 = 0, p3 = 0;
    for (int q = 0; q < 16; ++q) {
      double h0 = md[0][c_local][p0]; int i0 = mi[0][c_local][p0];
      double h1 = md[1][c_local][p1]; int i1 = mi[1][c_local][p1];
      double h2 = md[2][c_local][p2]; int i2 = mi[2][c_local][p2];
      double h3 = md[3][c_local][p3]; int i3 = mi[3][c_local][p3];
      bool a01 = (h1 < h0) || (h1 == h0 && i1 < i0);
      double ha = a01 ? h1 : h0; int ia = a01 ? i1 : i0; int wa = a01 ? 1 : 0;
      bool a23 = (h3 < h2) || (h3 == h2 && i3 < i2);
      double hb = a23 ? h3 : h2; int ib = a23 ? i3 : i2; int wb = a23 ? 3 : 2;
      bool ab = (hb < ha) || (hb == ha && ib < ia);
      int win = ab ? wb : wa; int iw = ab ? ib : ia;
      p0 += (win == 0); p1 += (win == 1); p2 += (win == 2); p3 += (win == 3);
      int gidx = gbase + iw;
      nbr[(size_t)n * KNN + q] = gidx;
      atomicAdd(&counts[gidx], 1);
    }
  }
}

__global__ void scan_k(const int* __restrict__ counts, int* __restrict__ cursor) {
  __shared__ int part[256];
  int t = threadIdx.x, base = t * 256;
  int s = 0;
  for (int i = 0; i < 256; ++i) s += counts[base + i];
  part[t] = s;
  __syncthreads();
  if (t == 0) {
    int run = 0;
    for (int i = 0; i < 256; ++i) { int v = part[i]; part[i] = run; run += v; }
  }
  __syncthreads();
  int run = part[t];
  for (int i = 0; i < 256; ++i) { int idx = base + i; cursor[idx] = run; run += counts[idx]; }
}

__global__ void scatter_k(const int* __restrict__ nbr, int* __restrict__ cursor,
                          int* __restrict__ srow, int* __restrict__ scol) {
  int e = blockIdx.x * 256 + threadIdx.x;
  int r = nbr[e], c = e >> 4;
  int pos = atomicAdd(&cursor[r], 1);
  srow[pos] = r; scol[pos] = c;
}

// Per 128-edge tile: h1 = relu(P[row]+Q'[col]) fp32 -> split bf16 hi/lo -> swizzled LDS;
// split-precision MFMA vs W2 hi/lo frags; relu(+b2) -> swizzled LDS f32; segmented sum.
__global__ __launch_bounds__(256) void gemm2_k(const float* __restrict__ PQ,
                                               const int* __restrict__ srow, const int* __restrict__ scol,
                                               const unsigned short* __restrict__ w2h,
                                               const unsigned short* __restrict__ w2l,
                                               const float* __restrict__ b2,
                                               float* __restrict__ out) {
  __shared__ __attribute__((aligned(16))) char smem[65536];
  float* h2 = (float*)smem;
  int tid = threadIdx.x, lane = tid & 63, wave = tid >> 6;
  int cg = wave & 1, eg = wave >> 1;
  s16x8 bh[4][4], bl[4][4];
#pragma unroll
  for (int ct = 0; ct < 4; ++ct)
#pragma unroll
    for (int ks = 0; ks < 4; ++ks) {
      int off = (((cg * 4 + ct) * 4 + ks) * 64 + lane) * 8;
      bh[ct][ks] = *(const s16x8*)(w2h + off);
      bl[ct][ks] = *(const s16x8*)(w2l + off);
    }
  float b2r[4];
#pragma unroll
  for (int ct = 0; ct < 4; ++ct) b2r[ct] = b2[cg * 64 + ct * 16 + (lane & 15)];

  for (int tile = blockIdx.x; tile < NEDGE / 128; tile += gridDim.x) {
    int base = tile * 128;
    {
      int e_in = tid >> 1, c0 = (tid & 1) * 64;
      int e = base + e_in;
      int row = srow[e], colc = scol[e];
      const float* Pp = PQ + (size_t)row * 256 + c0;
      const float* Qp = PQ + (size_t)colc * 256 + 128 + c0;
#pragma unroll
      for (int cc = 0; cc < 64; cc += 8) {
        f32x4 p0 = *(const f32x4*)(Pp + cc);
        f32x4 p1 = *(const f32x4*)(Pp + cc + 4);
        f32x4 q0 = *(const f32x4*)(Qp + cc);
        f32x4 q1 = *(const f32x4*)(Qp + cc + 4);
        s16x8 hv, lv;
#pragma unroll
        for (int k2 = 0; k2 < 4; ++k2) {
          float sv = p0[k2] + q0[k2];
          sv = sv > 0.f ? sv : 0.f;
          unsigned short hi = f2bf(sv);
          hv[k2] = (short)hi; lv[k2] = (short)f2bf(sv - bf2f(hi));
          float sw = p1[k2] + q1[k2];
          sw = sw > 0.f ? sw : 0.f;
          unsigned short hj = f2bf(sw);
          hv[4 + k2] = (short)hj; lv[4 + k2] = (short)f2bf(sw - bf2f(hj));
        }
        int byteoff = e_in * 256 + (((c0 + cc) * 2) ^ ((e_in & 7) << 4));
        *(s16x8*)(smem + byteoff) = hv;
        *(s16x8*)(smem + 32768 + byteoff) = lv;
      }
    }
    __syncthreads();
    f32x4 acc[4][4];
#pragma unroll
    for (int rt = 0; rt < 4; ++rt)
#pragma unroll
      for (int ct = 0; ct < 4; ++ct) acc[rt][ct] = (f32x4){0.f, 0.f, 0.f, 0.f};
#pragma unroll
    for (int rt = 0; rt < 4; ++rt) {
      int rowL = eg * 64 + rt * 16 + (lane & 15);
#pragma unroll
      for (int ks = 0; ks < 4; ++ks) {
        int byteoff = rowL * 256 + ((16 * (lane >> 4) + 64 * ks) ^ ((rowL & 7) << 4));
        s16x8 a_hi = *(const s16x8*)(smem + byteoff);
        s16x8 a_lo = *(const s16x8*)(smem + 32768 + byteoff);
#pragma unroll
        for (int ct = 0; ct < 4; ++ct) {
          acc[rt][ct] = __builtin_amdgcn_mfma_f32_16x16x32_bf16(a_hi, bh[ct][ks], acc[rt][ct], 0, 0, 0);
          acc[rt][ct] = __builtin_amdgcn_mfma_f32_16x16x32_bf16(a_hi, bl[ct][ks], acc[rt][ct], 0, 0, 0);
          acc[rt][ct] = __builtin_amdgcn_mfma_f32_16x16x32_bf16(a_lo, bh[ct][ks], acc[rt][ct], 0, 0, 0);
        }
      }
    }
    __syncthreads();
#pragma unroll
    for (int rt = 0; rt < 4; ++rt)
#pragma unroll
      for (int ct = 0; ct < 4; ++ct) {
        int col = cg * 64 + ct * 16 + (lane & 15);
#pragma unroll
        for (int r = 0; r < 4; ++r) {
          int row_in = eg * 64 + rt * 16 + (lane >> 4) * 4 + r;
          float v = acc[rt][ct][r] + b2r[ct];
          v = v > 0.f ? v : 0.f;
          int gq = (row_in >> 2) & 3;
          h2[row_in * 128 + (col ^ (gq << 2) ^ ((gq & 1) << 4))] = v;
        }
      }
    __syncthreads();
    {
      int col = tid & 127, estart = (tid >> 7) * 64;
      float a = 0.f;
      int prev = srow[base + estart];
#pragma unroll 8
      for (int e2 = estart; e2 < estart + 64; ++e2) {
        int r2 = srow[base + e2];
        if (r2 != prev) { atomicAdd(out + (size_t)prev * 128 + col, a); a = 0.f; prev = r2; }
        int gq = (e2 >> 2) & 3;
        a += h2[e2 * 128 + (col ^ (gq << 2) ^ ((gq & 1) << 4))];
      }
      atomicAdd(out + (size_t)prev * 128 + col, a);
    }
    __syncthreads();
  }
}

__global__ void final_k(float* __restrict__ out, const int* __restrict__ counts) {
  int idx = blockIdx.x * 256 + threadIdx.x;
  int n = idx >> 7;
  int c = counts[n];
  c = c > 0 ? c : 1;
  out[idx] = out[idx] / (float)c;
}

extern "C" void kernel_launch(void* const* d_in, const int* in_sizes, int n_in,
                              void* d_out, int out_size, void* d_ws, size_t ws_size,
                              hipStream_t stream) {
  const float* x = (const float*)d_in[0];
  const float* W1 = (const float*)d_in[2];
  const float* b1 = (const float*)d_in[3];
  const float* W2 = (const float*)d_in[4];
  const float* b2 = (const float*)d_in[5];
  float* out = (float*)d_out;
  char* ws = (char*)d_ws;

  float* PQ = (float*)(ws + 0);                            // 67,108,864 B
  float* sq = (float*)(ws + 67108864);                     //    262,144 B
  int* nbr = (int*)(ws + 67371008);                        //  4,194,304 B
  int* counts = (int*)(ws + 71565312);                     //    262,144 B
  int* cursor = (int*)(ws + 71827456);                     //    262,144 B
  int* srow = (int*)(ws + 72089600);                       //  4,194,304 B
  int* scol = (int*)(ws + 76283904);                       //  4,194,304 B
  unsigned short* w2h = (unsigned short*)(ws + 80478208);  //     32,768 B
  unsigned short* w2l = (unsigned short*)(ws + 80510976);  //     32,768 B
  double* sq64 = (double*)(ws + 80543744);                 //    524,288 B  (end 81,068,032)

  hipMemsetAsync(d_out, 0, (size_t)out_size * sizeof(float), stream);
  hipMemsetAsync(counts, 0, (size_t)N_NODES * sizeof(int), stream);
  prep_weights_k<<<1, 256, 0, stream>>>(W2, w2h, w2l);
  prep_sq_k<<<N_NODES / 256, 256, 0, stream>>>(x, sq, sq64);
  prep_pq_k<<<N_NODES / 16, 256, 0, stream>>>(x, W1, b1, PQ);
  knn_k<<<N_NODES / 64, 256, 0, stream>>>(x, sq, sq64, nbr, counts);
  scan_k<<<1, 256, 0, stream>>>(counts, cursor);
  scatter_k<<<NEDGE / 256, 256, 0, stream>>>(nbr, cursor, srow, scol);
  gemm2_k<<<512, 256, 0, stream>>>(PQ, srow, scol, w2h, w2l, b2, out);
  final_k<<<(N_NODES * HDIM) / 256, 256, 0, stream>>>(out, counts);
}

// Round 5
// 3200.280 us; speedup vs baseline: 1.2222x; 1.2222x over previous
//
#include <hip/hip_runtime.h>

typedef __attribute__((ext_vector_type(4))) float f32x4;
typedef __attribute__((ext_vector_type(8))) short s16x8;

#define N_NODES 65536
#define GNPG 1024
#define FDIM 64
#define HDIM 128
#define KNN 16
#define SUB 8
#define SCAND 18
#define MCAND 24
#define NEDGE (N_NODES * KNN)

__device__ __forceinline__ unsigned short f2bf(float f) {
  union { float f; unsigned int u; } v; v.f = f;
  unsigned int r = v.u + 0x7FFFu + ((v.u >> 16) & 1u);
  return (unsigned short)(r >> 16);
}
__device__ __forceinline__ float bf2f(unsigned short u) {
  union { unsigned int u; float f; } v; v.u = ((unsigned int)u) << 16;
  return v.f;
}

// Build MFMA B-fragment-ordered hi/lo bf16 split of W2 (128x128).
__global__ void prep_weights_k(const float* __restrict__ W2,
                               unsigned short* __restrict__ w2h, unsigned short* __restrict__ w2l) {
  int tid = threadIdx.x;
  for (int idx = tid; idx < 8 * 4 * 64 * 8; idx += 256) {
    int j = idx & 7, l = (idx >> 3) & 63, ks = (idx >> 9) & 3, ct = idx >> 11;
    int k = 8 * (l >> 4) + j + 32 * ks, col = ct * 16 + (l & 15);
    float v = W2[k * 128 + col];
    unsigned short hi = f2bf(v);
    w2h[idx] = hi;
    w2l[idx] = f2bf(v - bf2f(hi));
  }
}

// sq in f64 (exact reference-side values) + f32 copy for the candidate pass.
__global__ void prep_sq_k(const float* __restrict__ x, float* __restrict__ sq,
                          double* __restrict__ sq64) {
  int n = blockIdx.x * 256 + threadIdx.x;
  const f32x4* xp = (const f32x4*)(x + (size_t)n * FDIM);
  double s0 = 0, s1 = 0, s2 = 0, s3 = 0;
#pragma unroll
  for (int f = 0; f < 16; ++f) {
    f32x4 a = xp[f];
    s0 = fma((double)a[0], (double)a[0], s0);
    s1 = fma((double)a[1], (double)a[1], s1);
    s2 = fma((double)a[2], (double)a[2], s2);
    s3 = fma((double)a[3], (double)a[3], s3);
  }
  double s = (s0 + s1) + (s2 + s3);
  sq64[n] = s;
  sq[n] = (float)s;
}

// Full-fp32 GEMM1: PQ[n][0:128] = x[n]@(W1_top - W1_bot); PQ[n][128:256] = x[n]@W1_bot + b1.
__global__ __launch_bounds__(256) void prep_pq_k(const float* __restrict__ x,
                                                 const float* __restrict__ W1,
                                                 const float* __restrict__ b1,
                                                 float* __restrict__ PQ) {
  __shared__ float WcL[64 * 256];   // 64KB
  __shared__ float xL[16 * 64];     // 4KB
  int tid = threadIdx.x;
  for (int i = tid; i < 64 * 256; i += 256) {
    int k = i >> 8, c = i & 255;
    WcL[i] = (c < 128) ? (W1[k * 128 + c] - W1[(k + 64) * 128 + c])
                       : W1[(k + 64) * 128 + (c - 128)];
  }
  int nbase = blockIdx.x * 16;
  for (int i = tid; i < 16 * 64; i += 256) xL[i] = x[(size_t)nbase * 64 + i];
  __syncthreads();
  int nl = tid >> 4, c0 = tid & 15;
  float acc[16];
#pragma unroll
  for (int j = 0; j < 16; ++j) acc[j] = 0.f;
  for (int k = 0; k < 64; ++k) {
    float xk = xL[nl * 64 + k];
    const float* wr = WcL + k * 256 + c0;
#pragma unroll
    for (int j = 0; j < 16; ++j) acc[j] = fmaf(xk, wr[16 * j], acc[j]);
  }
#pragma unroll
  for (int j = 0; j < 16; ++j) {
    int c = c0 + 16 * j;
    float b = (c >= 128) ? b1[c - 128] : 0.f;
    PQ[(size_t)(nbase + nl) * 256 + c] = acc[j] + b;
  }
}

// KNN stage 1: 8 threads per center (subset s takes jl = 8*i+s). Register f32 top-18 of the
// 128-candidate subset. No f64, no merge — just dump (d, idx) to ws. ~115 live VGPRs.
__global__ __launch_bounds__(256) void knn1_k(const float* __restrict__ x, const float* __restrict__ sq,
                                              float* __restrict__ candd,
                                              unsigned short* __restrict__ candi) {
  __shared__ float sq_l[GNPG];
  int tid = threadIdx.x;
  int c_local = tid >> 3, s = tid & 7;
  int n = blockIdx.x * 32 + c_local;
  int gbase = n & ~(GNPG - 1);
  int nl = n & (GNPG - 1);
  for (int i = tid; i < GNPG; i += 256) sq_l[i] = sq[gbase + i];
  __syncthreads();
  f32x4 xi[16];
  const f32x4* xp = (const f32x4*)(x + (size_t)n * FDIM);
#pragma unroll
  for (int f = 0; f < 16; ++f) xi[f] = xp[f];
  float sqi = sq_l[nl];
  float dl[SCAND]; int il[SCAND];
#pragma unroll
  for (int q = 0; q < SCAND; ++q) { dl[q] = 3.0e38f; il[q] = 0; }
#pragma unroll 2
  for (int i = 0; i < GNPG / SUB; ++i) {
    int jl = SUB * i + s;
    const f32x4* xj = (const f32x4*)(x + (size_t)(gbase + jl) * FDIM);
    float s0 = 0, s1 = 0, s2 = 0, s3 = 0;
#pragma unroll
    for (int f = 0; f < 16; ++f) {
      f32x4 a = xi[f], b = xj[f];
      s0 = fmaf(a[0], b[0], s0); s1 = fmaf(a[1], b[1], s1);
      s2 = fmaf(a[2], b[2], s2); s3 = fmaf(a[3], b[3], s3);
    }
    float dot = (s0 + s1) + (s2 + s3);
    float d = sqi + sq_l[jl] - 2.f * dot;
    if (jl != nl && d < dl[SCAND - 1]) {
      dl[SCAND - 1] = d; il[SCAND - 1] = jl;
#pragma unroll
      for (int p = SCAND - 1; p >= 1; --p) {
        float a0 = dl[p - 1], a1 = dl[p];
        int b0 = il[p - 1], b1v = il[p];
        bool c = a1 < a0;
        dl[p - 1] = c ? a1 : a0; dl[p] = c ? a0 : a1;
        il[p - 1] = c ? b1v : b0; il[p] = c ? b0 : b1v;
      }
    }
  }
  float* dd = candd + (size_t)n * (SUB * SCAND) + s * SCAND;
  unsigned short* ii = candi + (size_t)n * (SUB * SCAND) + s * SCAND;
#pragma unroll
  for (int q = 0; q < SCAND; ++q) { dd[q] = dl[q]; ii[q] = (unsigned short)il[q]; }
}

// KNN stage 2: one thread per center. f32-insert 144 -> top-24 (margin 8), fully-unrolled
// f64 rescore of the 24, selection sort top-16 by (d64, idx), write nbr + counts.
__global__ __launch_bounds__(256) void knn2_k(const float* __restrict__ x,
                                              const double* __restrict__ sq64,
                                              const float* __restrict__ candd,
                                              const unsigned short* __restrict__ candi,
                                              int* __restrict__ nbr, int* __restrict__ counts) {
  int n = blockIdx.x * 256 + threadIdx.x;
  int gbase = n & ~(GNPG - 1);
  float dl[MCAND]; int il[MCAND];
#pragma unroll
  for (int q = 0; q < MCAND; ++q) { dl[q] = 3.0e38f; il[q] = 0; }
  const float* dd = candd + (size_t)n * (SUB * SCAND);
  const unsigned short* ii = candi + (size_t)n * (SUB * SCAND);
  for (int t = 0; t < SUB * SCAND; ++t) {
    float d = dd[t];
    int j = ii[t];
    if (d < dl[MCAND - 1]) {
      dl[MCAND - 1] = d; il[MCAND - 1] = j;
#pragma unroll
      for (int p = MCAND - 1; p >= 1; --p) {
        float a0 = dl[p - 1], a1 = dl[p];
        int b0 = il[p - 1], b1v = il[p];
        bool c = a1 < a0;
        dl[p - 1] = c ? a1 : a0; dl[p] = c ? a0 : a1;
        il[p - 1] = c ? b1v : b0; il[p] = c ? b0 : b1v;
      }
    }
  }
  f32x4 xi[16];
  const f32x4* xp = (const f32x4*)(x + (size_t)n * FDIM);
#pragma unroll
  for (int f = 0; f < 16; ++f) xi[f] = xp[f];
  double d64[MCAND];
  double sq64i = sq64[n];
#pragma unroll
  for (int q = 0; q < MCAND; ++q) {
    int j = gbase + il[q];
    const f32x4* xj = (const f32x4*)(x + (size_t)j * FDIM);
    double t0 = 0, t1 = 0, t2 = 0, t3 = 0;
#pragma unroll
    for (int f = 0; f < 16; ++f) {
      f32x4 a = xi[f], b = xj[f];
      t0 = fma((double)a[0], (double)b[0], t0);
      t1 = fma((double)a[1], (double)b[1], t1);
      t2 = fma((double)a[2], (double)b[2], t2);
      t3 = fma((double)a[3], (double)b[3], t3);
    }
    d64[q] = sq64i + sq64[j] - 2.0 * ((t0 + t1) + (t2 + t3));
  }
#pragma unroll
  for (int a = 0; a < KNN; ++a)
#pragma unroll
    for (int b = a + 1; b < MCAND; ++b) {
      bool sw = (d64[b] < d64[a]) || (d64[b] == d64[a] && il[b] < il[a]);
      double td = sw ? d64[b] : d64[a];
      double tu = sw ? d64[a] : d64[b];
      int ti = sw ? il[b] : il[a];
      int tv = sw ? il[a] : il[b];
      d64[a] = td; d64[b] = tu; il[a] = ti; il[b] = tv;
    }
#pragma unroll
  for (int q = 0; q < KNN; ++q) {
    int gidx = gbase + il[q];
    nbr[(size_t)n * KNN + q] = gidx;
    atomicAdd(&counts[gidx], 1);
  }
}

__global__ void scan_k(const int* __restrict__ counts, int* __restrict__ cursor) {
  __shared__ int part[256];
  int t = threadIdx.x, base = t * 256;
  int s = 0;
  for (int i = 0; i < 256; ++i) s += counts[base + i];
  part[t] = s;
  __syncthreads();
  if (t == 0) {
    int run = 0;
    for (int i = 0; i < 256; ++i) { int v = part[i]; part[i] = run; run += v; }
  }
  __syncthreads();
  int run = part[t];
  for (int i = 0; i < 256; ++i) { int idx = base + i; cursor[idx] = run; run += counts[idx]; }
}

__global__ void scatter_k(const int* __restrict__ nbr, int* __restrict__ cursor,
                          int* __restrict__ srow, int* __restrict__ scol) {
  int e = blockIdx.x * 256 + threadIdx.x;
  int r = nbr[e], c = e >> 4;
  int pos = atomicAdd(&cursor[r], 1);
  srow[pos] = r; scol[pos] = c;
}

// Per 128-edge tile: h1 = relu(P[row]+Q'[col]) fp32 -> split bf16 hi/lo -> swizzled LDS;
// split-precision MFMA vs W2 hi/lo frags; relu(+b2) -> swizzled LDS f32; segmented sum.
__global__ __launch_bounds__(256) void gemm2_k(const float* __restrict__ PQ,
                                               const int* __restrict__ srow, const int* __restrict__ scol,
                                               const unsigned short* __restrict__ w2h,
                                               const unsigned short* __restrict__ w2l,
                                               const float* __restrict__ b2,
                                               float* __restrict__ out) {
  __shared__ __attribute__((aligned(16))) char smem[65536];
  float* h2 = (float*)smem;
  int tid = threadIdx.x, lane = tid & 63, wave = tid >> 6;
  int cg = wave & 1, eg = wave >> 1;
  s16x8 bh[4][4], bl[4][4];
#pragma unroll
  for (int ct = 0; ct < 4; ++ct)
#pragma unroll
    for (int ks = 0; ks < 4; ++ks) {
      int off = (((cg * 4 + ct) * 4 + ks) * 64 + lane) * 8;
      bh[ct][ks] = *(const s16x8*)(w2h + off);
      bl[ct][ks] = *(const s16x8*)(w2l + off);
    }
  float b2r[4];
#pragma unroll
  for (int ct = 0; ct < 4; ++ct) b2r[ct] = b2[cg * 64 + ct * 16 + (lane & 15)];

  for (int tile = blockIdx.x; tile < NEDGE / 128; tile += gridDim.x) {
    int base = tile * 128;
    {
      int e_in = tid >> 1, c0 = (tid & 1) * 64;
      int e = base + e_in;
      int row = srow[e], colc = scol[e];
      const float* Pp = PQ + (size_t)row * 256 + c0;
      const float* Qp = PQ + (size_t)colc * 256 + 128 + c0;
#pragma unroll
      for (int cc = 0; cc < 64; cc += 8) {
        f32x4 p0 = *(const f32x4*)(Pp + cc);
        f32x4 p1 = *(const f32x4*)(Pp + cc + 4);
        f32x4 q0 = *(const f32x4*)(Qp + cc);
        f32x4 q1 = *(const f32x4*)(Qp + cc + 4);
        s16x8 hv, lv;
#pragma unroll
        for (int k2 = 0; k2 < 4; ++k2) {
          float sv = p0[k2] + q0[k2];
          sv = sv > 0.f ? sv : 0.f;
          unsigned short hi = f2bf(sv);
          hv[k2] = (short)hi; lv[k2] = (short)f2bf(sv - bf2f(hi));
          float sw = p1[k2] + q1[k2];
          sw = sw > 0.f ? sw : 0.f;
          unsigned short hj = f2bf(sw);
          hv[4 + k2] = (short)hj; lv[4 + k2] = (short)f2bf(sw - bf2f(hj));
        }
        int byteoff = e_in * 256 + (((c0 + cc) * 2) ^ ((e_in & 7) << 4));
        *(s16x8*)(smem + byteoff) = hv;
        *(s16x8*)(smem + 32768 + byteoff) = lv;
      }
    }
    __syncthreads();
    f32x4 acc[4][4];
#pragma unroll
    for (int rt = 0; rt < 4; ++rt)
#pragma unroll
      for (int ct = 0; ct < 4; ++ct) acc[rt][ct] = (f32x4){0.f, 0.f, 0.f, 0.f};
#pragma unroll
    for (int rt = 0; rt < 4; ++rt) {
      int rowL = eg * 64 + rt * 16 + (lane & 15);
#pragma unroll
      for (int ks = 0; ks < 4; ++ks) {
        int byteoff = rowL * 256 + ((16 * (lane >> 4) + 64 * ks) ^ ((rowL & 7) << 4));
        s16x8 a_hi = *(const s16x8*)(smem + byteoff);
        s16x8 a_lo = *(const s16x8*)(smem + 32768 + byteoff);
#pragma unroll
        for (int ct = 0; ct < 4; ++ct) {
          acc[rt][ct] = __builtin_amdgcn_mfma_f32_16x16x32_bf16(a_hi, bh[ct][ks], acc[rt][ct], 0, 0, 0);
          acc[rt][ct] = __builtin_amdgcn_mfma_f32_16x16x32_bf16(a_hi, bl[ct][ks], acc[rt][ct], 0, 0, 0);
          acc[rt][ct] = __builtin_amdgcn_mfma_f32_16x16x32_bf16(a_lo, bh[ct][ks], acc[rt][ct], 0, 0, 0);
        }
      }
    }
    __syncthreads();
#pragma unroll
    for (int rt = 0; rt < 4; ++rt)
#pragma unroll
      for (int ct = 0; ct < 4; ++ct) {
        int col = cg * 64 + ct * 16 + (lane & 15);
#pragma unroll
        for (int r = 0; r < 4; ++r) {
          int row_in = eg * 64 + rt * 16 + (lane >> 4) * 4 + r;
          float v = acc[rt][ct][r] + b2r[ct];
          v = v > 0.f ? v : 0.f;
          int gq = (row_in >> 2) & 3;
          h2[row_in * 128 + (col ^ (gq << 2) ^ ((gq & 1) << 4))] = v;
        }
      }
    __syncthreads();
    {
      int col = tid & 127, estart = (tid >> 7) * 64;
      float a = 0.f;
      int prev = srow[base + estart];
#pragma unroll 8
      for (int e2 = estart; e2 < estart + 64; ++e2) {
        int r2 = srow[base + e2];
        if (r2 != prev) { atomicAdd(out + (size_t)prev * 128 + col, a); a = 0.f; prev = r2; }
        int gq = (e2 >> 2) & 3;
        a += h2[e2 * 128 + (col ^ (gq << 2) ^ ((gq & 1) << 4))];
      }
      atomicAdd(out + (size_t)prev * 128 + col, a);
    }
    __syncthreads();
  }
}

__global__ void final_k(float* __restrict__ out, const int* __restrict__ counts) {
  int idx = blockIdx.x * 256 + threadIdx.x;
  int n = idx >> 7;
  int c = counts[n];
  c = c > 0 ? c : 1;
  out[idx] = out[idx] / (float)c;
}

extern "C" void kernel_launch(void* const* d_in, const int* in_sizes, int n_in,
                              void* d_out, int out_size, void* d_ws, size_t ws_size,
                              hipStream_t stream) {
  const float* x = (const float*)d_in[0];
  const float* W1 = (const float*)d_in[2];
  const float* b1 = (const float*)d_in[3];
  const float* W2 = (const float*)d_in[4];
  const float* b2 = (const float*)d_in[5];
  float* out = (float*)d_out;
  char* ws = (char*)d_ws;

  // PQ region (64 MB) is aliased by the KNN candidate buffers: knn1/knn2 run BEFORE
  // prep_pq_k writes PQ, so the lifetimes are disjoint (stream-ordered).
  float* PQ = (float*)(ws + 0);                            // 67,108,864 B
  float* candd = (float*)(ws + 0);                         // 37,748,736 B (alias PQ)
  unsigned short* candi = (unsigned short*)(ws + 37748736);// 18,874,368 B (alias PQ)
  float* sq = (float*)(ws + 67108864);                     //    262,144 B
  int* nbr = (int*)(ws + 67371008);                        //  4,194,304 B
  int* counts = (int*)(ws + 71565312);                     //    262,144 B
  int* cursor = (int*)(ws + 71827456);                     //    262,144 B
  int* srow = (int*)(ws + 72089600);                       //  4,194,304 B
  int* scol = (int*)(ws + 76283904);                       //  4,194,304 B
  unsigned short* w2h = (unsigned short*)(ws + 80478208);  //     32,768 B
  unsigned short* w2l = (unsigned short*)(ws + 80510976);  //     32,768 B
  double* sq64 = (double*)(ws + 80543744);                 //    524,288 B  (end 81,068,032)

  hipMemsetAsync(d_out, 0, (size_t)out_size * sizeof(float), stream);
  hipMemsetAsync(counts, 0, (size_t)N_NODES * sizeof(int), stream);
  prep_weights_k<<<1, 256, 0, stream>>>(W2, w2h, w2l);
  prep_sq_k<<<N_NODES / 256, 256, 0, stream>>>(x, sq, sq64);
  knn1_k<<<N_NODES / 32, 256, 0, stream>>>(x, sq, candd, candi);
  knn2_k<<<N_NODES / 256, 256, 0, stream>>>(x, sq64, candd, candi, nbr, counts);
  scan_k<<<1, 256, 0, stream>>>(counts, cursor);
  scatter_k<<<NEDGE / 256, 256, 0, stream>>>(nbr, cursor, srow, scol);
  prep_pq_k<<<N_NODES / 16, 256, 0, stream>>>(x, W1, b1, PQ);
  gemm2_k<<<512, 256, 0, stream>>>(PQ, srow, scol, w2h, w2l, b2, out);
  final_k<<<(N_NODES * HDIM) / 256, 256, 0, stream>>>(out, counts);
}

// Round 6
// 1436.295 us; speedup vs baseline: 2.7231x; 2.2281x over previous
//
#include <hip/hip_runtime.h>

typedef __attribute__((ext_vector_type(4))) float f32x4;
typedef __attribute__((ext_vector_type(8))) short s16x8;

#define N_NODES 65536
#define GNPG 1024
#define FDIM 64
#define HDIM 128
#define KNN 16
#define JT 64      // j-tile (cols per KNN iteration)
#define DSTR 68    // dist LDS row stride (f32), padded vs 64 to break bank conflicts
#define SCAND 20   // per-subset candidate list (2 subsets/center)
#define MCAND 24   // merged f32 superset re-ranked in f64
#define NEDGE (N_NODES * KNN)

__device__ __forceinline__ unsigned short f2bf(float f) {
  union { float f; unsigned int u; } v; v.f = f;
  unsigned int r = v.u + 0x7FFFu + ((v.u >> 16) & 1u);
  return (unsigned short)(r >> 16);
}
__device__ __forceinline__ float bf2f(unsigned short u) {
  union { unsigned int u; float f; } v; v.u = ((unsigned int)u) << 16;
  return v.f;
}

// Build MFMA B-fragment-ordered hi/lo bf16 split of W2 (128x128).
__global__ void prep_weights_k(const float* __restrict__ W2,
                               unsigned short* __restrict__ w2h, unsigned short* __restrict__ w2l) {
  int tid = threadIdx.x;
  for (int idx = tid; idx < 8 * 4 * 64 * 8; idx += 256) {
    int j = idx & 7, l = (idx >> 3) & 63, ks = (idx >> 9) & 3, ct = idx >> 11;
    int k = 8 * (l >> 4) + j + 32 * ks, col = ct * 16 + (l & 15);
    float v = W2[k * 128 + col];
    unsigned short hi = f2bf(v);
    w2h[idx] = hi;
    w2l[idx] = f2bf(v - bf2f(hi));
  }
}

// Per-node precompute: f64 sq norm (+f32 copy) and the bf16 hi/lo split of x (row-major,
// which IS the MFMA A/B fragment element order when read 8-consecutive-k at a time).
__global__ void prep_node_k(const float* __restrict__ x, float* __restrict__ sq,
                            double* __restrict__ sq64,
                            unsigned short* __restrict__ xh, unsigned short* __restrict__ xl) {
  int n = blockIdx.x * 256 + threadIdx.x;
  const f32x4* xp = (const f32x4*)(x + (size_t)n * FDIM);
  double s0 = 0, s1 = 0;
#pragma unroll
  for (int c8 = 0; c8 < 8; ++c8) {
    f32x4 a = xp[2 * c8], b = xp[2 * c8 + 1];
    s16x8 h, l;
#pragma unroll
    for (int e = 0; e < 4; ++e) {
      unsigned short hi = f2bf(a[e]);
      h[e] = (short)hi; l[e] = (short)f2bf(a[e] - bf2f(hi));
      unsigned short hj = f2bf(b[e]);
      h[4 + e] = (short)hj; l[4 + e] = (short)f2bf(b[e] - bf2f(hj));
      s0 = fma((double)a[e], (double)a[e], s0);
      s1 = fma((double)b[e], (double)b[e], s1);
    }
    *(s16x8*)(xh + (size_t)n * FDIM + c8 * 8) = h;
    *(s16x8*)(xl + (size_t)n * FDIM + c8 * 8) = l;
  }
  double s = s0 + s1;
  sq64[n] = s;
  sq[n] = (float)s;
}

// Full-fp32 GEMM1: PQ[n][0:128] = x[n]@(W1_top - W1_bot); PQ[n][128:256] = x[n]@W1_bot + b1.
__global__ __launch_bounds__(256) void prep_pq_k(const float* __restrict__ x,
                                                 const float* __restrict__ W1,
                                                 const float* __restrict__ b1,
                                                 float* __restrict__ PQ) {
  __shared__ float WcL[64 * 256];   // 64KB
  __shared__ float xL[16 * 64];     // 4KB
  int tid = threadIdx.x;
  for (int i = tid; i < 64 * 256; i += 256) {
    int k = i >> 8, c = i & 255;
    WcL[i] = (c < 128) ? (W1[k * 128 + c] - W1[(k + 64) * 128 + c])
                       : W1[(k + 64) * 128 + (c - 128)];
  }
  int nbase = blockIdx.x * 16;
  for (int i = tid; i < 16 * 64; i += 256) xL[i] = x[(size_t)nbase * 64 + i];
  __syncthreads();
  int nl = tid >> 4, c0 = tid & 15;
  float acc[16];
#pragma unroll
  for (int j = 0; j < 16; ++j) acc[j] = 0.f;
  for (int k = 0; k < 64; ++k) {
    float xk = xL[nl * 64 + k];
    const float* wr = WcL + k * 256 + c0;
#pragma unroll
    for (int j = 0; j < 16; ++j) acc[j] = fmaf(xk, wr[16 * j], acc[j]);
  }
#pragma unroll
  for (int j = 0; j < 16; ++j) {
    int c = c0 + 16 * j;
    float b = (c >= 128) ? b1[c - 128] : 0.f;
    PQ[(size_t)(nbase + nl) * 256 + c] = acc[j] + b;
  }
}

// KNN stage 1 (MFMA): block = 128 centers of one graph. Per 64-col tile: stage split-bf16
// B-frags in LDS, 48 MFMA/wave (hi*hi+hi*lo+lo*hi => ~f32-accurate dots), distances ->
// padded LDS, then 2 threads/center scan 32 cols each keeping a register top-20.
__global__ __launch_bounds__(256) void knn1_k(const unsigned short* __restrict__ xh,
                                              const unsigned short* __restrict__ xl,
                                              const float* __restrict__ sq,
                                              float* __restrict__ candd,
                                              unsigned short* __restrict__ candi) {
  __shared__ float sq_l[GNPG];
  __shared__ __attribute__((aligned(16))) unsigned short bhL[512 * 8];
  __shared__ __attribute__((aligned(16))) unsigned short blL[512 * 8];
  __shared__ __attribute__((aligned(16))) float distL[128 * DSTR];
  int tid = threadIdx.x, lane = tid & 63, wave = tid >> 6;
  int g = blockIdx.x >> 3;
  int rb = (blockIdx.x & 7) * 128;
  const unsigned short* xhg = xh + (size_t)g * GNPG * FDIM;
  const unsigned short* xlg = xl + (size_t)g * GNPG * FDIM;
  for (int i = tid; i < GNPG; i += 256) sq_l[i] = sq[g * GNPG + i];
  // A-frags (hi/lo) for this wave's 32 rows: A[m=lane&15][k=8*(lane>>4)+j+32ks]
  s16x8 ah[2][2], al[2][2];
#pragma unroll
  for (int rt = 0; rt < 2; ++rt)
#pragma unroll
    for (int ks = 0; ks < 2; ++ks) {
      size_t off = (size_t)(rb + wave * 32 + rt * 16 + (lane & 15)) * FDIM + (lane >> 4) * 8 + 32 * ks;
      ah[rt][ks] = *(const s16x8*)(xhg + off);
      al[rt][ks] = *(const s16x8*)(xlg + off);
    }
  float dl[SCAND]; int il[SCAND];
#pragma unroll
  for (int q = 0; q < SCAND; ++q) { dl[q] = 3.0e38f; il[q] = 0; }
  int c = tid >> 1, sub = tid & 1;
  for (int jt = 0; jt < GNPG / JT; ++jt) {
    // stage B-frags: B[k=8*(l>>4)+j+32ks][col=ct*16+(l&15)] = x[col-node][k]
#pragma unroll
    for (int s2 = tid; s2 < 512; s2 += 256) {
      int ct = s2 >> 7, ks = (s2 >> 6) & 1, l = s2 & 63;
      size_t goff = (size_t)(jt * JT + ct * 16 + (l & 15)) * FDIM + (l >> 4) * 8 + 32 * ks;
      *(s16x8*)(bhL + s2 * 8) = *(const s16x8*)(xhg + goff);
      *(s16x8*)(blL + s2 * 8) = *(const s16x8*)(xlg + goff);
    }
    __syncthreads();
    f32x4 acc[2][4];
#pragma unroll
    for (int rt = 0; rt < 2; ++rt)
#pragma unroll
      for (int ct = 0; ct < 4; ++ct) acc[rt][ct] = (f32x4){0.f, 0.f, 0.f, 0.f};
#pragma unroll
    for (int ks = 0; ks < 2; ++ks)
#pragma unroll
      for (int ct = 0; ct < 4; ++ct) {
        s16x8 bhr = *(const s16x8*)(bhL + ((ct * 2 + ks) * 64 + lane) * 8);
        s16x8 blr = *(const s16x8*)(blL + ((ct * 2 + ks) * 64 + lane) * 8);
#pragma unroll
        for (int rt = 0; rt < 2; ++rt) {
          acc[rt][ct] = __builtin_amdgcn_mfma_f32_16x16x32_bf16(ah[rt][ks], bhr, acc[rt][ct], 0, 0, 0);
          acc[rt][ct] = __builtin_amdgcn_mfma_f32_16x16x32_bf16(ah[rt][ks], blr, acc[rt][ct], 0, 0, 0);
          acc[rt][ct] = __builtin_amdgcn_mfma_f32_16x16x32_bf16(al[rt][ks], bhr, acc[rt][ct], 0, 0, 0);
        }
      }
    // distances to LDS; C layout: col=lane&15, row=(lane>>4)*4+r
#pragma unroll
    for (int rt = 0; rt < 2; ++rt)
#pragma unroll
      for (int ct = 0; ct < 4; ++ct) {
        int coltl = ct * 16 + (lane & 15);
        int jlg = jt * JT + coltl;
        float sqj = sq_l[jlg];
#pragma unroll
        for (int r = 0; r < 4; ++r) {
          int row = wave * 32 + rt * 16 + (lane >> 4) * 4 + r;
          float d = sq_l[rb + row] + sqj - 2.f * acc[rt][ct][r];
          if (rb + row == jlg) d = 3.0e38f;
          distL[row * DSTR + coltl] = d;
        }
      }
    __syncthreads();
    // scan: thread (c,sub) scans 32 cols of center c's row
#pragma unroll 2
    for (int i = 0; i < 8; ++i) {
      f32x4 v = *(const f32x4*)(distL + c * DSTR + sub * 32 + i * 4);
#pragma unroll
      for (int e = 0; e < 4; ++e) {
        float d = v[e];
        if (d < dl[SCAND - 1]) {
          dl[SCAND - 1] = d; il[SCAND - 1] = jt * JT + sub * 32 + i * 4 + e;
#pragma unroll
          for (int p = SCAND - 1; p >= 1; --p) {
            float a0 = dl[p - 1], a1 = dl[p];
            int b0 = il[p - 1], b1v = il[p];
            bool cc = a1 < a0;
            dl[p - 1] = cc ? a1 : a0; dl[p] = cc ? a0 : a1;
            il[p - 1] = cc ? b1v : b0; il[p] = cc ? b0 : b1v;
          }
        }
      }
    }
  }
  int nglob = g * GNPG + rb + c;
  float* dd = candd + (size_t)nglob * (2 * SCAND) + sub * SCAND;
  unsigned short* ii = candi + (size_t)nglob * (2 * SCAND) + sub * SCAND;
#pragma unroll
  for (int q = 0; q < SCAND; ++q) { dd[q] = dl[q]; ii[q] = (unsigned short)il[q]; }
}

// KNN stage 2: one thread per center. f32-insert 40 -> top-24, fully-unrolled f64 rescore,
// selection sort top-16 by (d64, idx), write nbr + counts.
__global__ __launch_bounds__(256) void knn2_k(const float* __restrict__ x,
                                              const double* __restrict__ sq64,
                                              const float* __restrict__ candd,
                                              const unsigned short* __restrict__ candi,
                                              int* __restrict__ nbr, int* __restrict__ counts) {
  int n = blockIdx.x * 256 + threadIdx.x;
  int gbase = n & ~(GNPG - 1);
  float dl[MCAND]; int il[MCAND];
#pragma unroll
  for (int q = 0; q < MCAND; ++q) { dl[q] = 3.0e38f; il[q] = 0; }
  const float* dd = candd + (size_t)n * (2 * SCAND);
  const unsigned short* ii = candi + (size_t)n * (2 * SCAND);
  for (int t = 0; t < 2 * SCAND; ++t) {
    float d = dd[t];
    int j = ii[t];
    if (d < dl[MCAND - 1]) {
      dl[MCAND - 1] = d; il[MCAND - 1] = j;
#pragma unroll
      for (int p = MCAND - 1; p >= 1; --p) {
        float a0 = dl[p - 1], a1 = dl[p];
        int b0 = il[p - 1], b1v = il[p];
        bool c = a1 < a0;
        dl[p - 1] = c ? a1 : a0; dl[p] = c ? a0 : a1;
        il[p - 1] = c ? b1v : b0; il[p] = c ? b0 : b1v;
      }
    }
  }
  f32x4 xi[16];
  const f32x4* xp = (const f32x4*)(x + (size_t)n * FDIM);
#pragma unroll
  for (int f = 0; f < 16; ++f) xi[f] = xp[f];
  double d64[MCAND];
  double sq64i = sq64[n];
#pragma unroll
  for (int q = 0; q < MCAND; ++q) {
    int j = gbase + il[q];
    const f32x4* xj = (const f32x4*)(x + (size_t)j * FDIM);
    double t0 = 0, t1 = 0, t2 = 0, t3 = 0;
#pragma unroll
    for (int f = 0; f < 16; ++f) {
      f32x4 a = xi[f], b = xj[f];
      t0 = fma((double)a[0], (double)b[0], t0);
      t1 = fma((double)a[1], (double)b[1], t1);
      t2 = fma((double)a[2], (double)b[2], t2);
      t3 = fma((double)a[3], (double)b[3], t3);
    }
    d64[q] = sq64i + sq64[j] - 2.0 * ((t0 + t1) + (t2 + t3));
  }
#pragma unroll
  for (int a = 0; a < KNN; ++a)
#pragma unroll
    for (int b = a + 1; b < MCAND; ++b) {
      bool sw = (d64[b] < d64[a]) || (d64[b] == d64[a] && il[b] < il[a]);
      double td = sw ? d64[b] : d64[a];
      double tu = sw ? d64[a] : d64[b];
      int ti = sw ? il[b] : il[a];
      int tv = sw ? il[a] : il[b];
      d64[a] = td; d64[b] = tu; il[a] = ti; il[b] = tv;
    }
#pragma unroll
  for (int q = 0; q < KNN; ++q) {
    int gidx = gbase + il[q];
    nbr[(size_t)n * KNN + q] = gidx;
    atomicAdd(&counts[gidx], 1);
  }
}

__global__ void scan_k(const int* __restrict__ counts, int* __restrict__ cursor) {
  __shared__ int part[256];
  int t = threadIdx.x, base = t * 256;
  int s = 0;
  for (int i = 0; i < 256; ++i) s += counts[base + i];
  part[t] = s;
  __syncthreads();
  if (t == 0) {
    int run = 0;
    for (int i = 0; i < 256; ++i) { int v = part[i]; part[i] = run; run += v; }
  }
  __syncthreads();
  int run = part[t];
  for (int i = 0; i < 256; ++i) { int idx = base + i; cursor[idx] = run; run += counts[idx]; }
}

__global__ void scatter_k(const int* __restrict__ nbr, int* __restrict__ cursor,
                          int* __restrict__ srow, int* __restrict__ scol) {
  int e = blockIdx.x * 256 + threadIdx.x;
  int r = nbr[e], c = e >> 4;
  int pos = atomicAdd(&cursor[r], 1);
  srow[pos] = r; scol[pos] = c;
}

// Per 128-edge tile: h1 = relu(P[row]+Q'[col]) fp32 -> split bf16 hi/lo -> swizzled LDS;
// split-precision MFMA vs W2 hi/lo frags; relu(+b2) -> swizzled LDS f32; segmented sum.
__global__ __launch_bounds__(256) void gemm2_k(const float* __restrict__ PQ,
                                               const int* __restrict__ srow, const int* __restrict__ scol,
                                               const unsigned short* __restrict__ w2h,
                                               const unsigned short* __restrict__ w2l,
                                               const float* __restrict__ b2,
                                               float* __restrict__ out) {
  __shared__ __attribute__((aligned(16))) char smem[65536];
  float* h2 = (float*)smem;
  int tid = threadIdx.x, lane = tid & 63, wave = tid >> 6;
  int cg = wave & 1, eg = wave >> 1;
  s16x8 bh[4][4], bl[4][4];
#pragma unroll
  for (int ct = 0; ct < 4; ++ct)
#pragma unroll
    for (int ks = 0; ks < 4; ++ks) {
      int off = (((cg * 4 + ct) * 4 + ks) * 64 + lane) * 8;
      bh[ct][ks] = *(const s16x8*)(w2h + off);
      bl[ct][ks] = *(const s16x8*)(w2l + off);
    }
  float b2r[4];
#pragma unroll
  for (int ct = 0; ct < 4; ++ct) b2r[ct] = b2[cg * 64 + ct * 16 + (lane & 15)];

  for (int tile = blockIdx.x; tile < NEDGE / 128; tile += gridDim.x) {
    int base = tile * 128;
    {
      int e_in = tid >> 1, c0 = (tid & 1) * 64;
      int e = base + e_in;
      int row = srow[e], colc = scol[e];
      const float* Pp = PQ + (size_t)row * 256 + c0;
      const float* Qp = PQ + (size_t)colc * 256 + 128 + c0;
#pragma unroll
      for (int cc = 0; cc < 64; cc += 8) {
        f32x4 p0 = *(const f32x4*)(Pp + cc);
        f32x4 p1 = *(const f32x4*)(Pp + cc + 4);
        f32x4 q0 = *(const f32x4*)(Qp + cc);
        f32x4 q1 = *(const f32x4*)(Qp + cc + 4);
        s16x8 hv, lv;
#pragma unroll
        for (int k2 = 0; k2 < 4; ++k2) {
          float sv = p0[k2] + q0[k2];
          sv = sv > 0.f ? sv : 0.f;
          unsigned short hi = f2bf(sv);
          hv[k2] = (short)hi; lv[k2] = (short)f2bf(sv - bf2f(hi));
          float sw = p1[k2] + q1[k2];
          sw = sw > 0.f ? sw : 0.f;
          unsigned short hj = f2bf(sw);
          hv[4 + k2] = (short)hj; lv[4 + k2] = (short)f2bf(sw - bf2f(hj));
        }
        int byteoff = e_in * 256 + (((c0 + cc) * 2) ^ ((e_in & 7) << 4));
        *(s16x8*)(smem + byteoff) = hv;
        *(s16x8*)(smem + 32768 + byteoff) = lv;
      }
    }
    __syncthreads();
    f32x4 acc[4][4];
#pragma unroll
    for (int rt = 0; rt < 4; ++rt)
#pragma unroll
      for (int ct = 0; ct < 4; ++ct) acc[rt][ct] = (f32x4){0.f, 0.f, 0.f, 0.f};
#pragma unroll
    for (int rt = 0; rt < 4; ++rt) {
      int rowL = eg * 64 + rt * 16 + (lane & 15);
#pragma unroll
      for (int ks = 0; ks < 4; ++ks) {
        int byteoff = rowL * 256 + ((16 * (lane >> 4) + 64 * ks) ^ ((rowL & 7) << 4));
        s16x8 a_hi = *(const s16x8*)(smem + byteoff);
        s16x8 a_lo = *(const s16x8*)(smem + 32768 + byteoff);
#pragma unroll
        for (int ct = 0; ct < 4; ++ct) {
          acc[rt][ct] = __builtin_amdgcn_mfma_f32_16x16x32_bf16(a_hi, bh[ct][ks], acc[rt][ct], 0, 0, 0);
          acc[rt][ct] = __builtin_amdgcn_mfma_f32_16x16x32_bf16(a_hi, bl[ct][ks], acc[rt][ct], 0, 0, 0);
          acc[rt][ct] = __builtin_amdgcn_mfma_f32_16x16x32_bf16(a_lo, bh[ct][ks], acc[rt][ct], 0, 0, 0);
        }
      }
    }
    __syncthreads();
#pragma unroll
    for (int rt = 0; rt < 4; ++rt)
#pragma unroll
      for (int ct = 0; ct < 4; ++ct) {
        int col = cg * 64 + ct * 16 + (lane & 15);
#pragma unroll
        for (int r = 0; r < 4; ++r) {
          int row_in = eg * 64 + rt * 16 + (lane >> 4) * 4 + r;
          float v = acc[rt][ct][r] + b2r[ct];
          v = v > 0.f ? v : 0.f;
          int gq = (row_in >> 2) & 3;
          h2[row_in * 128 + (col ^ (gq << 2) ^ ((gq & 1) << 4))] = v;
        }
      }
    __syncthreads();
    {
      int col = tid & 127, estart = (tid >> 7) * 64;
      float a = 0.f;
      int prev = srow[base + estart];
#pragma unroll 8
      for (int e2 = estart; e2 < estart + 64; ++e2) {
        int r2 = srow[base + e2];
        if (r2 != prev) { atomicAdd(out + (size_t)prev * 128 + col, a); a = 0.f; prev = r2; }
        int gq = (e2 >> 2) & 3;
        a += h2[e2 * 128 + (col ^ (gq << 2) ^ ((gq & 1) << 4))];
      }
      atomicAdd(out + (size_t)prev * 128 + col, a);
    }
    __syncthreads();
  }
}

__global__ void final_k(float* __restrict__ out, const int* __restrict__ counts) {
  int idx = blockIdx.x * 256 + threadIdx.x;
  int n = idx >> 7;
  int c = counts[n];
  c = c > 0 ? c : 1;
  out[idx] = out[idx] / (float)c;
}

extern "C" void kernel_launch(void* const* d_in, const int* in_sizes, int n_in,
                              void* d_out, int out_size, void* d_ws, size_t ws_size,
                              hipStream_t stream) {
  const float* x = (const float*)d_in[0];
  const float* W1 = (const float*)d_in[2];
  const float* b1 = (const float*)d_in[3];
  const float* W2 = (const float*)d_in[4];
  const float* b2 = (const float*)d_in[5];
  float* out = (float*)d_out;
  char* ws = (char*)d_ws;

  // PQ region (64 MB) is aliased by KNN-phase buffers (candd/candi/xh/xl): all KNN kernels
  // run BEFORE prep_pq_k writes PQ, so lifetimes are disjoint (stream-ordered).
  float* PQ = (float*)(ws + 0);                            // 67,108,864 B
  float* candd = (float*)(ws + 0);                         // 10,485,760 B (alias PQ)
  unsigned short* candi = (unsigned short*)(ws + 10485760);//  5,242,880 B (alias PQ)
  unsigned short* xh = (unsigned short*)(ws + 16777216);   //  8,388,608 B (alias PQ)
  unsigned short* xl = (unsigned short*)(ws + 25165824);   //  8,388,608 B (alias PQ)
  float* sq = (float*)(ws + 67108864);                     //    262,144 B
  int* nbr = (int*)(ws + 67371008);                        //  4,194,304 B
  int* counts = (int*)(ws + 71565312);                     //    262,144 B
  int* cursor = (int*)(ws + 71827456);                     //    262,144 B
  int* srow = (int*)(ws + 72089600);                       //  4,194,304 B
  int* scol = (int*)(ws + 76283904);                       //  4,194,304 B
  unsigned short* w2h = (unsigned short*)(ws + 80478208);  //     32,768 B
  unsigned short* w2l = (unsigned short*)(ws + 80510976);  //     32,768 B
  double* sq64 = (double*)(ws + 80543744);                 //    524,288 B  (end 81,068,032)

  hipMemsetAsync(d_out, 0, (size_t)out_size * sizeof(float), stream);
  hipMemsetAsync(counts, 0, (size_t)N_NODES * sizeof(int), stream);
  prep_weights_k<<<1, 256, 0, stream>>>(W2, w2h, w2l);
  prep_node_k<<<N_NODES / 256, 256, 0, stream>>>(x, sq, sq64, xh, xl);
  knn1_k<<<N_NODES / 128, 256, 0, stream>>>(xh, xl, sq, candd, candi);
  knn2_k<<<N_NODES / 256, 256, 0, stream>>>(x, sq64, candd, candi, nbr, counts);
  scan_k<<<1, 256, 0, stream>>>(counts, cursor);
  scatter_k<<<NEDGE / 256, 256, 0, stream>>>(nbr, cursor, srow, scol);
  prep_pq_k<<<N_NODES / 16, 256, 0, stream>>>(x, W1, b1, PQ);
  gemm2_k<<<512, 256, 0, stream>>>(PQ, srow, scol, w2h, w2l, b2, out);
  final_k<<<(N_NODES * HDIM) / 256, 256, 0, stream>>>(out, counts);
}

// Round 7
// 1269.654 us; speedup vs baseline: 3.0805x; 1.1312x over previous
//
#include <hip/hip_runtime.h>

typedef __attribute__((ext_vector_type(4))) float f32x4;
typedef __attribute__((ext_vector_type(8))) short s16x8;
typedef __attribute__((ext_vector_type(8))) _Float16 f16x8;

#define N_NODES 65536
#define GNPG 1024
#define FDIM 64
#define HDIM 128
#define KNN 16
#define JT 64      // knn j-tile
#define DSTR 68    // knn dist LDS row stride (f32)
#define SCAND 20   // per-subset candidate list (2 subsets/center)
#define MCAND 24   // merged f32 superset re-ranked in f64
#define NEDGE (N_NODES * KNN)

// Build MFMA B-fragment-ordered fp16 copy of W2 (128x128).
// Frag layout (16x16x32): lane l holds B[k = 8*(l>>4)+j + 32*ks][col = ct*16 + (l&15)], j=0..7.
__global__ void prep_weights_k(const float* __restrict__ W2, _Float16* __restrict__ w2f) {
  int tid = threadIdx.x;
  for (int idx = tid; idx < 8 * 4 * 64 * 8; idx += 256) {
    int j = idx & 7, l = (idx >> 3) & 63, ks = (idx >> 9) & 3, ct = idx >> 11;
    int k = 8 * (l >> 4) + j + 32 * ks, col = ct * 16 + (l & 15);
    w2f[idx] = (_Float16)W2[k * 128 + col];
  }
}

// Per-node precompute: f64 sq norm (+f32 copy) and fp16 copy of x (row-major = frag order).
__global__ void prep_node_k(const float* __restrict__ x, float* __restrict__ sq,
                            double* __restrict__ sq64, _Float16* __restrict__ xf) {
  int n = blockIdx.x * 256 + threadIdx.x;
  const f32x4* xp = (const f32x4*)(x + (size_t)n * FDIM);
  double s0 = 0, s1 = 0;
#pragma unroll
  for (int c8 = 0; c8 < 8; ++c8) {
    f32x4 a = xp[2 * c8], b = xp[2 * c8 + 1];
    f16x8 h;
#pragma unroll
    for (int e = 0; e < 4; ++e) {
      h[e] = (_Float16)a[e];
      h[4 + e] = (_Float16)b[e];
      s0 = fma((double)a[e], (double)a[e], s0);
      s1 = fma((double)b[e], (double)b[e], s1);
    }
    *(f16x8*)(xf + (size_t)n * FDIM + c8 * 8) = h;
  }
  double s = s0 + s1;
  sq64[n] = s;
  sq[n] = (float)s;
}

// Full-fp32 GEMM1: PQ[n][0:128] = x[n]@(W1_top - W1_bot); PQ[n][128:256] = x[n]@W1_bot + b1.
__global__ __launch_bounds__(256) void prep_pq_k(const float* __restrict__ x,
                                                 const float* __restrict__ W1,
                                                 const float* __restrict__ b1,
                                                 float* __restrict__ PQ) {
  __shared__ float WcL[64 * 256];   // 64KB
  __shared__ float xL[16 * 64];     // 4KB
  int tid = threadIdx.x;
  for (int i = tid; i < 64 * 256; i += 256) {
    int k = i >> 8, c = i & 255;
    WcL[i] = (c < 128) ? (W1[k * 128 + c] - W1[(k + 64) * 128 + c])
                       : W1[(k + 64) * 128 + (c - 128)];
  }
  int nbase = blockIdx.x * 16;
  for (int i = tid; i < 16 * 64; i += 256) xL[i] = x[(size_t)nbase * 64 + i];
  __syncthreads();
  int nl = tid >> 4, c0 = tid & 15;
  float acc[16];
#pragma unroll
  for (int j = 0; j < 16; ++j) acc[j] = 0.f;
  for (int k = 0; k < 64; ++k) {
    float xk = xL[nl * 64 + k];
    const float* wr = WcL + k * 256 + c0;
#pragma unroll
    for (int j = 0; j < 16; ++j) acc[j] = fmaf(xk, wr[16 * j], acc[j]);
  }
#pragma unroll
  for (int j = 0; j < 16; ++j) {
    int c = c0 + 16 * j;
    float b = (c >= 128) ? b1[c - 128] : 0.f;
    PQ[(size_t)(nbase + nl) * 256 + c] = acc[j] + b;
  }
}

// KNN stage 1 (fp16 MFMA): block = 128 centers of one graph. Per 64-col tile: stage fp16
// B-frags in LDS, 16 MFMA/wave, distances -> padded LDS, 2 threads/center scan 32 cols
// each keeping a register top-20. fp16 distance noise ~0.014 << superset margin; the f64
// rescore in knn2 is the correctness authority.
__global__ __launch_bounds__(256) void knn1_k(const _Float16* __restrict__ xf,
                                              const float* __restrict__ sq,
                                              float* __restrict__ candd,
                                              unsigned short* __restrict__ candi) {
  __shared__ float sq_l[GNPG];
  __shared__ __attribute__((aligned(16))) _Float16 bfL[512 * 8];
  __shared__ __attribute__((aligned(16))) float distL[128 * DSTR];
  int tid = threadIdx.x, lane = tid & 63, wave = tid >> 6;
  int g = blockIdx.x >> 3;
  int rb = (blockIdx.x & 7) * 128;
  const _Float16* xfg = xf + (size_t)g * GNPG * FDIM;
  for (int i = tid; i < GNPG; i += 256) sq_l[i] = sq[g * GNPG + i];
  f16x8 af[2][2];
#pragma unroll
  for (int rt = 0; rt < 2; ++rt)
#pragma unroll
    for (int ks = 0; ks < 2; ++ks) {
      size_t off = (size_t)(rb + wave * 32 + rt * 16 + (lane & 15)) * FDIM + (lane >> 4) * 8 + 32 * ks;
      af[rt][ks] = *(const f16x8*)(xfg + off);
    }
  float dl[SCAND]; int il[SCAND];
#pragma unroll
  for (int q = 0; q < SCAND; ++q) { dl[q] = 3.0e38f; il[q] = 0; }
  int c = tid >> 1, sub = tid & 1;
  for (int jt = 0; jt < GNPG / JT; ++jt) {
#pragma unroll
    for (int s2 = tid; s2 < 512; s2 += 256) {
      int ct = s2 >> 7, ks = (s2 >> 6) & 1, l = s2 & 63;
      size_t goff = (size_t)(jt * JT + ct * 16 + (l & 15)) * FDIM + (l >> 4) * 8 + 32 * ks;
      *(f16x8*)(bfL + s2 * 8) = *(const f16x8*)(xfg + goff);
    }
    __syncthreads();
    f32x4 acc[2][4];
#pragma unroll
    for (int rt = 0; rt < 2; ++rt)
#pragma unroll
      for (int ct = 0; ct < 4; ++ct) acc[rt][ct] = (f32x4){0.f, 0.f, 0.f, 0.f};
#pragma unroll
    for (int ks = 0; ks < 2; ++ks)
#pragma unroll
      for (int ct = 0; ct < 4; ++ct) {
        f16x8 bfr = *(const f16x8*)(bfL + ((ct * 2 + ks) * 64 + lane) * 8);
#pragma unroll
        for (int rt = 0; rt < 2; ++rt)
          acc[rt][ct] = __builtin_amdgcn_mfma_f32_16x16x32_f16(af[rt][ks], bfr, acc[rt][ct], 0, 0, 0);
      }
#pragma unroll
    for (int rt = 0; rt < 2; ++rt)
#pragma unroll
      for (int ct = 0; ct < 4; ++ct) {
        int coltl = ct * 16 + (lane & 15);
        int jlg = jt * JT + coltl;
        float sqj = sq_l[jlg];
#pragma unroll
        for (int r = 0; r < 4; ++r) {
          int row = wave * 32 + rt * 16 + (lane >> 4) * 4 + r;
          float d = sq_l[rb + row] + sqj - 2.f * acc[rt][ct][r];
          if (rb + row == jlg) d = 3.0e38f;
          distL[row * DSTR + coltl] = d;
        }
      }
    __syncthreads();
#pragma unroll 2
    for (int i = 0; i < 8; ++i) {
      f32x4 v = *(const f32x4*)(distL + c * DSTR + sub * 32 + i * 4);
#pragma unroll
      for (int e = 0; e < 4; ++e) {
        float d = v[e];
        if (d < dl[SCAND - 1]) {
          dl[SCAND - 1] = d; il[SCAND - 1] = jt * JT + sub * 32 + i * 4 + e;
#pragma unroll
          for (int p = SCAND - 1; p >= 1; --p) {
            float a0 = dl[p - 1], a1 = dl[p];
            int b0 = il[p - 1], b1v = il[p];
            bool cc = a1 < a0;
            dl[p - 1] = cc ? a1 : a0; dl[p] = cc ? a0 : a1;
            il[p - 1] = cc ? b1v : b0; il[p] = cc ? b0 : b1v;
          }
        }
      }
    }
  }
  int nglob = g * GNPG + rb + c;
  float* dd = candd + (size_t)nglob * (2 * SCAND) + sub * SCAND;
  unsigned short* ii = candi + (size_t)nglob * (2 * SCAND) + sub * SCAND;
#pragma unroll
  for (int q = 0; q < SCAND; ++q) { dd[q] = dl[q]; ii[q] = (unsigned short)il[q]; }
}

// KNN stage 2: one thread per center. f32-insert 40 -> top-24, fully-unrolled f64 rescore,
// selection sort top-16 by (d64, idx), write nbr + counts.
__global__ __launch_bounds__(256) void knn2_k(const float* __restrict__ x,
                                              const double* __restrict__ sq64,
                                              const float* __restrict__ candd,
                                              const unsigned short* __restrict__ candi,
                                              int* __restrict__ nbr, int* __restrict__ counts) {
  int n = blockIdx.x * 256 + threadIdx.x;
  int gbase = n & ~(GNPG - 1);
  float dl[MCAND]; int il[MCAND];
#pragma unroll
  for (int q = 0; q < MCAND; ++q) { dl[q] = 3.0e38f; il[q] = 0; }
  const float* dd = candd + (size_t)n * (2 * SCAND);
  const unsigned short* ii = candi + (size_t)n * (2 * SCAND);
  for (int t = 0; t < 2 * SCAND; ++t) {
    float d = dd[t];
    int j = ii[t];
    if (d < dl[MCAND - 1]) {
      dl[MCAND - 1] = d; il[MCAND - 1] = j;
#pragma unroll
      for (int p = MCAND - 1; p >= 1; --p) {
        float a0 = dl[p - 1], a1 = dl[p];
        int b0 = il[p - 1], b1v = il[p];
        bool c = a1 < a0;
        dl[p - 1] = c ? a1 : a0; dl[p] = c ? a0 : a1;
        il[p - 1] = c ? b1v : b0; il[p] = c ? b0 : b1v;
      }
    }
  }
  f32x4 xi[16];
  const f32x4* xp = (const f32x4*)(x + (size_t)n * FDIM);
#pragma unroll
  for (int f = 0; f < 16; ++f) xi[f] = xp[f];
  double d64[MCAND];
  double sq64i = sq64[n];
#pragma unroll
  for (int q = 0; q < MCAND; ++q) {
    int j = gbase + il[q];
    const f32x4* xj = (const f32x4*)(x + (size_t)j * FDIM);
    double t0 = 0, t1 = 0, t2 = 0, t3 = 0;
#pragma unroll
    for (int f = 0; f < 16; ++f) {
      f32x4 a = xi[f], b = xj[f];
      t0 = fma((double)a[0], (double)b[0], t0);
      t1 = fma((double)a[1], (double)b[1], t1);
      t2 = fma((double)a[2], (double)b[2], t2);
      t3 = fma((double)a[3], (double)b[3], t3);
    }
    d64[q] = sq64i + sq64[j] - 2.0 * ((t0 + t1) + (t2 + t3));
  }
#pragma unroll
  for (int a = 0; a < KNN; ++a)
#pragma unroll
    for (int b = a + 1; b < MCAND; ++b) {
      bool sw = (d64[b] < d64[a]) || (d64[b] == d64[a] && il[b] < il[a]);
      double td = sw ? d64[b] : d64[a];
      double tu = sw ? d64[a] : d64[b];
      int ti = sw ? il[b] : il[a];
      int tv = sw ? il[a] : il[b];
      d64[a] = td; d64[b] = tu; il[a] = ti; il[b] = tv;
    }
#pragma unroll
  for (int q = 0; q < KNN; ++q) {
    int gidx = gbase + il[q];
    nbr[(size_t)n * KNN + q] = gidx;
    atomicAdd(&counts[gidx], 1);
  }
}

__global__ void scan_k(const int* __restrict__ counts, int* __restrict__ cursor) {
  __shared__ int part[256];
  int t = threadIdx.x, base = t * 256;
  int s = 0;
  for (int i = 0; i < 256; ++i) s += counts[base + i];
  part[t] = s;
  __syncthreads();
  if (t == 0) {
    int run = 0;
    for (int i = 0; i < 256; ++i) { int v = part[i]; part[i] = run; run += v; }
  }
  __syncthreads();
  int run = part[t];
  for (int i = 0; i < 256; ++i) { int idx = base + i; cursor[idx] = run; run += counts[idx]; }
}

__global__ void scatter_k(const int* __restrict__ nbr, int* __restrict__ cursor,
                          int* __restrict__ srow, int* __restrict__ scol) {
  int e = blockIdx.x * 256 + threadIdx.x;
  int r = nbr[e], c = e >> 4;
  int pos = atomicAdd(&cursor[r], 1);
  srow[pos] = r; scol[pos] = c;
}

// Per 64-edge tile: h1 = relu(P[row]+Q'[col]) fp32 -> fp16 -> swizzled LDS (16KB);
// fp16 MFMA vs W2 frags; relu(+b2) -> swizzled LDS f32 (32KB, aliases A after barrier);
// segmented sum by sorted row -> atomicAdd. 32KB LDS -> ~3 blocks/CU.
__global__ __launch_bounds__(256) void gemm2_k(const float* __restrict__ PQ,
                                               const int* __restrict__ srow, const int* __restrict__ scol,
                                               const _Float16* __restrict__ w2f,
                                               const float* __restrict__ b2,
                                               float* __restrict__ out) {
  __shared__ __attribute__((aligned(16))) char smem[32768];
  float* h2 = (float*)smem;
  int tid = threadIdx.x, lane = tid & 63, wave = tid >> 6;
  int cg = wave & 1, eg = wave >> 1;
  f16x8 wf[4][4];
#pragma unroll
  for (int ct = 0; ct < 4; ++ct)
#pragma unroll
    for (int ks = 0; ks < 4; ++ks)
      wf[ct][ks] = *(const f16x8*)(w2f + ((((cg * 4 + ct) * 4 + ks) * 64 + lane) * 8));
  float b2r[4];
#pragma unroll
  for (int ct = 0; ct < 4; ++ct) b2r[ct] = b2[cg * 64 + ct * 16 + (lane & 15)];

  for (int tile = blockIdx.x; tile < NEDGE / 64; tile += gridDim.x) {
    int base = tile * 64;
    {
      int e_in = tid >> 2, qq = tid & 3;
      int e = base + e_in;
      int row = srow[e], colc = scol[e];
      const float* Pp = PQ + (size_t)row * 256 + qq * 32;
      const float* Qp = PQ + (size_t)colc * 256 + 128 + qq * 32;
#pragma unroll
      for (int c8 = 0; c8 < 4; ++c8) {
        f32x4 p0 = *(const f32x4*)(Pp + c8 * 8);
        f32x4 p1 = *(const f32x4*)(Pp + c8 * 8 + 4);
        f32x4 q0 = *(const f32x4*)(Qp + c8 * 8);
        f32x4 q1 = *(const f32x4*)(Qp + c8 * 8 + 4);
        f16x8 hv;
#pragma unroll
        for (int k2 = 0; k2 < 4; ++k2) {
          float sv = p0[k2] + q0[k2];
          hv[k2] = (_Float16)(sv > 0.f ? sv : 0.f);
          float sw = p1[k2] + q1[k2];
          hv[4 + k2] = (_Float16)(sw > 0.f ? sw : 0.f);
        }
        int byteoff = e_in * 256 + ((2 * (qq * 32 + c8 * 8)) ^ ((e_in & 7) << 4));
        *(f16x8*)(smem + byteoff) = hv;
      }
    }
    __syncthreads();
    f32x4 acc[2][4];
#pragma unroll
    for (int rt = 0; rt < 2; ++rt)
#pragma unroll
      for (int ct = 0; ct < 4; ++ct) acc[rt][ct] = (f32x4){0.f, 0.f, 0.f, 0.f};
#pragma unroll
    for (int rt = 0; rt < 2; ++rt) {
      int rowL = eg * 32 + rt * 16 + (lane & 15);
#pragma unroll
      for (int ks = 0; ks < 4; ++ks) {
        int byteoff = rowL * 256 + ((16 * (lane >> 4) + 64 * ks) ^ ((rowL & 7) << 4));
        f16x8 a = *(const f16x8*)(smem + byteoff);
#pragma unroll
        for (int ct = 0; ct < 4; ++ct)
          acc[rt][ct] = __builtin_amdgcn_mfma_f32_16x16x32_f16(a, wf[ct][ks], acc[rt][ct], 0, 0, 0);
      }
    }
    __syncthreads();
#pragma unroll
    for (int rt = 0; rt < 2; ++rt)
#pragma unroll
      for (int ct = 0; ct < 4; ++ct) {
        int col = cg * 64 + ct * 16 + (lane & 15);
#pragma unroll
        for (int r = 0; r < 4; ++r) {
          int row_in = eg * 32 + rt * 16 + (lane >> 4) * 4 + r;
          float v = acc[rt][ct][r] + b2r[ct];
          v = v > 0.f ? v : 0.f;
          int gq = (row_in >> 2) & 3;
          h2[row_in * 128 + (col ^ (gq << 2) ^ ((gq & 1) << 4))] = v;
        }
      }
    __syncthreads();
    {
      int col = tid & 127, estart = (tid >> 7) * 32;
      float a = 0.f;
      int prev = srow[base + estart];
#pragma unroll 8
      for (int e2 = estart; e2 < estart + 32; ++e2) {
        int r2 = srow[base + e2];
        if (r2 != prev) { atomicAdd(out + (size_t)prev * 128 + col, a); a = 0.f; prev = r2; }
        int gq = (e2 >> 2) & 3;
        a += h2[e2 * 128 + (col ^ (gq << 2) ^ ((gq & 1) << 4))];
      }
      atomicAdd(out + (size_t)prev * 128 + col, a);
    }
    __syncthreads();
  }
}

__global__ void final_k(float* __restrict__ out, const int* __restrict__ counts) {
  int idx = blockIdx.x * 256 + threadIdx.x;
  int n = idx >> 7;
  int c = counts[n];
  c = c > 0 ? c : 1;
  out[idx] = out[idx] / (float)c;
}

extern "C" void kernel_launch(void* const* d_in, const int* in_sizes, int n_in,
                              void* d_out, int out_size, void* d_ws, size_t ws_size,
                              hipStream_t stream) {
  const float* x = (const float*)d_in[0];
  const float* W1 = (const float*)d_in[2];
  const float* b1 = (const float*)d_in[3];
  const float* W2 = (const float*)d_in[4];
  const float* b2 = (const float*)d_in[5];
  float* out = (float*)d_out;
  char* ws = (char*)d_ws;

  // PQ region (64 MB) is aliased by KNN-phase buffers (candd/candi/xf): all KNN kernels
  // run BEFORE prep_pq_k writes PQ, so lifetimes are disjoint (stream-ordered).
  float* PQ = (float*)(ws + 0);                            // 67,108,864 B
  float* candd = (float*)(ws + 0);                         // 10,485,760 B (alias PQ)
  unsigned short* candi = (unsigned short*)(ws + 10485760);//  5,242,880 B (alias PQ)
  _Float16* xf = (_Float16*)(ws + 16777216);               //  8,388,608 B (alias PQ)
  float* sq = (float*)(ws + 67108864);                     //    262,144 B
  int* nbr = (int*)(ws + 67371008);                        //  4,194,304 B
  int* counts = (int*)(ws + 71565312);                     //    262,144 B
  int* cursor = (int*)(ws + 71827456);                     //    262,144 B
  int* srow = (int*)(ws + 72089600);                       //  4,194,304 B
  int* scol = (int*)(ws + 76283904);                       //  4,194,304 B
  _Float16* w2f = (_Float16*)(ws + 80478208);              //     32,768 B
  double* sq64 = (double*)(ws + 80543744);                 //    524,288 B  (end 81,068,032)

  hipMemsetAsync(d_out, 0, (size_t)out_size * sizeof(float), stream);
  hipMemsetAsync(counts, 0, (size_t)N_NODES * sizeof(int), stream);
  prep_weights_k<<<1, 256, 0, stream>>>(W2, w2f);
  prep_node_k<<<N_NODES / 256, 256, 0, stream>>>(x, sq, sq64, xf);
  knn1_k<<<N_NODES / 128, 256, 0, stream>>>(xf, sq, candd, candi);
  knn2_k<<<N_NODES / 256, 256, 0, stream>>>(x, sq64, candd, candi, nbr, counts);
  scan_k<<<1, 256, 0, stream>>>(counts, cursor);
  scatter_k<<<NEDGE / 256, 256, 0, stream>>>(nbr, cursor, srow, scol);
  prep_pq_k<<<N_NODES / 16, 256, 0, stream>>>(x, W1, b1, PQ);
  gemm2_k<<<2048, 256, 0, stream>>>(PQ, srow, scol, w2f, b2, out);
  final_k<<<(N_NODES * HDIM) / 256, 256, 0, stream>>>(out, counts);
}